// Round 12
// baseline (209.814 us; speedup 1.0000x reference)
//
#include <hip/hip_runtime.h>
#include <math.h>

typedef __bf16 bf16;
typedef __attribute__((ext_vector_type(8))) __bf16 bf16x8;
typedef __attribute__((ext_vector_type(4))) float f32x4;
typedef __attribute__((ext_vector_type(16))) float f32x16;
typedef unsigned short u16;
typedef unsigned int u32;

constexpr int Nn = 8, Cc = 512, Ll = 2048, Hh = 8, Dd = 64;
constexpr float kScale = 0.044194173824159216f;           // 512^-0.5
constexpr float kQexp2 = kScale * 1.44269504088896341f;   // fold log2(e) into Q
constexpr size_t NCL = (size_t)Nn * Cc * Ll;
constexpr size_t WSZ = (size_t)Cc * Cc;

static __device__ __forceinline__ u16 bfbits(bf16 v) {
    union { bf16 b; u16 u; } x; x.b = v; return x.u;
}
static __device__ __forceinline__ float fexp2(float x) {
#if __has_builtin(__builtin_amdgcn_exp2f)
    return __builtin_amdgcn_exp2f(x);
#else
    return exp2f(x);
#endif
}

#define MFMA(a, b, c) __builtin_amdgcn_mfma_f32_16x16x32_bf16((a), (b), (c), 0, 0, 0)
#define MFMA32(a, b, c) __builtin_amdgcn_mfma_f32_32x32x16_bf16((a), (b), (c), 0, 0, 0)

static __device__ __forceinline__ void async16(const bf16* g, bf16* l) {
    __builtin_amdgcn_global_load_lds(
        (const __attribute__((address_space(1))) void*)g,
        (__attribute__((address_space(3))) void*)l, 16, 0, 0);
}

// pack two f32 -> one dword of 2 bf16 (RNE), lo in low half
static __device__ __forceinline__ u32 cvtpk(float lo, float hi) {
    u32 d;
    asm("v_cvt_pk_bf16_f32 %0, %1, %2" : "=v"(d) : "v"(lo), "v"(hi));
    return d;
}
// v_permlane32_swap_b32 vdst, vsrc: vdst lanes[32:63] <-> vsrc lanes[0:31]
//   => dst_new = [dst_lo | src_lo], src_new = [dst_hi | src_hi]
// NOTE: only safe with DISTINCT-valued operands (regalloc can coalesce
// equal-valued registers into one -> swap_b32 v,v destroys a half; this was
// the epilogue-L NaN root cause in v11/v12). All uses below have distinct
// cvtpk results as operands (the form v10/v13b compiled + passed with).
static __device__ __forceinline__ void swap32(u32& d, u32& s) {
    asm volatile("v_permlane32_swap_b32 %0, %1" : "+v"(d), "+v"(s));
}

// softmax a 16-wide St half (k16-block S within the 32-half), build PV A-frag.
// St[r]: S[k = 16*S + (r&3)+8*(r>>2)+4*hb][q = l31]; msk: triangular kc>l31.
// (kc formula includes the 16*S offset via 8*(r>>2).)
template<int S>
static __device__ __forceinline__ bf16x8 packP(const f32x16 St, bool msk,
                                               int hb, int l31, float& La)
{
    float p[8];
#pragma unroll
    for (int j = 0; j < 8; j++) {
        const int r = S * 8 + j;
        float pv = fexp2(St[r]);
        if (msk) {
            const int kc = (r & 3) + 8 * (r >> 2) + 4 * hb;
            if (kc > l31) pv = 0.f;
        }
        p[j] = pv;
    }
    La += ((p[0] + p[1]) + (p[2] + p[3])) + ((p[4] + p[5]) + (p[6] + p[7]));
    // lane values after cvtpk (lo-lane / hi-lane):
    //   A: k(0,1)/k(4,5)  B: k(2,3)/k(6,7)  C: k(8,9)/k(12,13) D: k(10,11)/k(14,15)
    u32 A = cvtpk(p[0], p[1]);
    u32 B = cvtpk(p[2], p[3]);
    u32 C = cvtpk(p[4], p[5]);
    u32 D = cvtpk(p[6], p[7]);
    // dst_hi <-> src_lo: A=[A_lo|C_lo], C=[A_hi|C_hi]; B=[B_lo|D_lo], D=[B_hi|D_hi]
    // -> lo-lane frag = k(0..7), hi-lane frag = k(8..15)  (MFMA32 A-layout)
    swap32(A, C);
    swap32(B, D);
    union { u32 w[4]; bf16x8 v; } pu;
    pu.w[0] = A; pu.w[1] = B; pu.w[2] = C; pu.w[3] = D;
    return pu.v;
}

// ---------------------------------------------------------------------------
// prep: z<8 -> x [n][c][l] fp32 -> xT [n][l][c] bf16 (64x64 tiles via LDS);
//       z==8 -> weights fp32 -> bf16.  grid (32, 8, 9), block 256.
// ---------------------------------------------------------------------------
__global__ __launch_bounds__(256) void prep_kernel(
    const float* __restrict__ x,
    const float* __restrict__ Wq, const float* __restrict__ Wk,
    const float* __restrict__ Wv, const float* __restrict__ Wo,
    bf16* __restrict__ xT, bf16* __restrict__ Wb)
{
    const int tid = threadIdx.x;
    if (blockIdx.z == Nn) {
        int gid = (blockIdx.y * 32 + blockIdx.x) * 256 + tid;   // 0..65535
        int w = gid >> 14;
        int o = (gid & 16383) * 4;                              // float4 base
        const float* src = (w == 0) ? Wq : (w == 1) ? Wk : (w == 2) ? Wv : Wo;
        bf16* dst = Wb + (size_t)w * WSZ;
#pragma unroll
        for (int j = 0; j < 4; j++) {
            float4 v = ((const float4*)src)[o + j];
            ushort4 u;
            u.x = bfbits((bf16)v.x); u.y = bfbits((bf16)v.y);
            u.z = bfbits((bf16)v.z); u.w = bfbits((bf16)v.w);
            *(ushort4*)(dst + (size_t)(o + j) * 4) = u;
        }
        return;
    }

    __shared__ bf16 Ts[64][72];
    const int lt = blockIdx.x, ct = blockIdx.y, n = blockIdx.z;

    const int cr = tid >> 2, l0 = (tid & 3) * 16;
    const float* src = x + ((size_t)(n * Cc + ct * 64 + cr)) * Ll + lt * 64 + l0;
#pragma unroll
    for (int i = 0; i < 4; i++) {
        float4 v = *(const float4*)(src + i * 4);
        Ts[l0 + i * 4 + 0][cr] = (bf16)v.x;
        Ts[l0 + i * 4 + 1][cr] = (bf16)v.y;
        Ts[l0 + i * 4 + 2][cr] = (bf16)v.z;
        Ts[l0 + i * 4 + 3][cr] = (bf16)v.w;
    }
    __syncthreads();

    const int lr = tid >> 2, c0 = (tid & 3) * 16;
    bf16* dst = xT + ((size_t)(n * Ll + lt * 64 + lr)) * Cc + ct * 64 + c0;
    *(bf16x8*)(dst)     = *(const bf16x8*)&Ts[lr][c0];
    *(bf16x8*)(dst + 8) = *(const bf16x8*)&Ts[lr][c0 + 8];
}

// ---------------------------------------------------------------------------
// QKV GEMM (m97 structure, unchanged). Q pre-scaled by kScale*log2e.
// ---------------------------------------------------------------------------
__global__ __launch_bounds__(256) void qkv_gemm(
    const bf16* __restrict__ xT, const bf16* __restrict__ Wb,
    bf16* __restrict__ Qt, bf16* __restrict__ Kt, bf16* __restrict__ Vb)
{
    const int lt = blockIdx.x, ow = blockIdx.y, n = blockIdx.z;
    const int widx = ow >> 2, otile = ow & 3;

    __shared__ bf16 Xs[128 * 64];
    __shared__ bf16 Ws[128 * 64];

    const int tid = threadIdx.x;
    const int lane = tid & 63, wv = tid >> 6;
    const int m = lane & 15, quad = lane >> 4;
    const int rh = wv & 1, ch = wv >> 1;

    const bf16* __restrict__ W = Wb + (size_t)widx * WSZ + (size_t)otile * 128 * Cc;
    const bf16* __restrict__ X = xT + (size_t)(n * Ll + lt * 128) * Cc;

    int srow[4], scol[4];
#pragma unroll
    for (int i = 0; i < 4; i++) {
        int q = i * 256 + tid;
        srow[i] = q >> 3;
        scol[i] = ((q ^ (q >> 3)) & 7) * 8;
    }

    f32x4 acc[4][4] = {};

    for (int c0 = 0; c0 < Cc; c0 += 64) {
#pragma unroll
        for (int i = 0; i < 4; i++)
            async16(&X[(size_t)srow[i] * Cc + c0 + scol[i]], &Xs[(i * 256 + tid) * 8]);
#pragma unroll
        for (int i = 0; i < 4; i++)
            async16(&W[(size_t)srow[i] * Cc + c0 + scol[i]], &Ws[(i * 256 + tid) * 8]);
        __syncthreads();

        const bf16* TA = (widx < 2) ? Xs : Ws;
        const bf16* TB = (widx < 2) ? Ws : Xs;
#pragma unroll
        for (int kk = 0; kk < 2; kk++) {
            const int sw = (((kk * 4 + quad) ^ (m & 7)) * 8);
            bf16x8 af[4], bfr[4];
#pragma unroll
            for (int t = 0; t < 4; t++)
                af[t] = *(const bf16x8*)&TA[(rh * 64 + t * 16 + m) * 64 + sw];
#pragma unroll
            for (int u = 0; u < 4; u++)
                bfr[u] = *(const bf16x8*)&TB[(ch * 64 + u * 16 + m) * 64 + sw];
#pragma unroll
            for (int t = 0; t < 4; t++)
#pragma unroll
                for (int u = 0; u < 4; u++)
                    acc[t][u] = MFMA(af[t], bfr[u], acc[t][u]);
        }
        __syncthreads();
    }

    if (widx < 2) {
        const float fq = (widx == 0) ? kQexp2 : 1.0f;
        bf16* __restrict__ OUT = (widx == 0) ? Qt : Kt;
#pragma unroll
        for (int u = 0; u < 4; u++) {
            const int o = otile * 128 + ch * 64 + u * 16 + m;
            const int h = o >> 6, d = o & 63;
            bf16* base = OUT + (size_t)(n * Hh + h) * Ll * Dd + d;
#pragma unroll
            for (int t = 0; t < 4; t++) {
                const int l0 = lt * 128 + rh * 64 + t * 16 + quad * 4;
#pragma unroll
                for (int r = 0; r < 4; r++)
                    base[(size_t)(l0 + r) * Dd] = (bf16)(acc[t][u][r] * fq);
            }
        }
    } else {
#pragma unroll
        for (int t = 0; t < 4; t++) {
            const int ob = otile * 128 + rh * 64 + t * 16 + quad * 4;
#pragma unroll
            for (int r = 0; r < 4; r++) {
                const int oo = ob + r, h = oo >> 6, d = oo & 63;
                bf16* base = Vb + ((size_t)(n * Hh + h) * Dd + d) * Ll;
#pragma unroll
                for (int u = 0; u < 4; u++)
                    base[lt * 128 + ch * 64 + u * 16 + m] = (bf16)acc[t][u][r];
            }
        }
    }
}

// ---------------------------------------------------------------------------
// Causal attention v16: v13b's verified skeleton (prefetch + __syncthreads,
// 2-buf, LDS epilogue) + 64 q-rows per WAVE: two 32-q groups g=0,1 share
// every K/V fragment read and its address math -> per-output LDS traffic
// and VALU both halve; per-wave ILP doubles (2 independent St/O chains).
// 4 waves x 64q = 256-q supertile; pairs {jp, 7-jp} -> uniform 36 k-iters;
// grid (h, 4, n) = 256 blocks = 1 block/CU, LDS 34 KB. Causal: wave diag
// tile = 4*st + wv; on it g=0 masks half i=0 / skips i=1, g=1 full i=0 /
// masks i=1 (v13b's verified per-64-row algebra, re-indexed).
// ---------------------------------------------------------------------------
__global__ __launch_bounds__(256, 1) void attn_mfma(
    const bf16* __restrict__ Qt, const bf16* __restrict__ Kt,
    const bf16* __restrict__ Vb, bf16* __restrict__ AO)
{
    const int h  = blockIdx.x;
    const int jp = blockIdx.y;   // 0..3 -> pair {jp, 7-jp}
    const int n  = blockIdx.z;

    __shared__ bf16 KV[2][2][64 * 64];   // [buf][K=0 / V^T=1] 32 KB
    __shared__ float Lsc[4][2][64];      // per-wave, per-group row-sum halves

    const int tid = threadIdx.x;
    const int lane = tid & 63, wv = tid >> 6;
    const int l31 = lane & 31, hb = lane >> 5;
    const int sw7 = l31 & 7;

    const size_t bnh = (size_t)(n * Hh + h) * Ll * Dd;
    const bf16* __restrict__ Qh = Qt + bnh;
    const bf16* __restrict__ Kh = Kt + bnh;
    const bf16* __restrict__ Vh = Vb + bnh;

    const int srow = tid >> 3;                        // 0..31
    const int scs  = (((tid & 7) ^ (srow & 7)) * 8);  // swizzled global chunk

#pragma unroll 1
    for (int ph = 0; ph < 2; ph++) {
        const int st = ph ? (7 - jp) : jp;      // supertile 0..7 (256 q-rows)
        const int nk = 4 * st + 4;
        const int dtile = 4 * st + wv;          // this wave's diagonal k-tile
        const int qbase = st * 256 + wv * 64;

        // Q as B-fragments: lane holds Q[q=qbase+32g+l31][d = s*16 + hb*8 + j]
        bf16x8 qf[2][4];
#pragma unroll
        for (int g = 0; g < 2; g++)
#pragma unroll
            for (int s = 0; s < 4; s++)
                qf[g][s] = *(const bf16x8*)
                    &Qh[(size_t)(qbase + 32 * g + l31) * Dd + s * 16 + hb * 8];

        f32x16 O00 = {}, O01 = {}, O10 = {}, O11 = {};   // O[g][dv-half]
        float La0 = 0.f, La1 = 0.f;

        // stage tile 0 -> buf 0 (v13b staging, byte-identical)
        async16(&Kh[(size_t)srow * Dd + scs],        &KV[0][0][(size_t)tid * 8]);
        async16(&Kh[(size_t)(srow + 32) * Dd + scs], &KV[0][0][(size_t)tid * 8 + 2048]);
        async16(&Vh[(size_t)srow * Ll + scs],        &KV[0][1][(size_t)tid * 8]);
        async16(&Vh[(size_t)(srow + 32) * Ll + scs], &KV[0][1][(size_t)tid * 8 + 2048]);
        __syncthreads();   // drains asyncs

        for (int kt = 0; kt < nk; kt++) {
            const int cur = kt & 1;

            if (kt + 1 < nk) {   // prefetch next tile into the other buffer
                const int kn = (kt + 1) * 64;
                async16(&Kh[(size_t)(kn + srow) * Dd + scs],      &KV[cur ^ 1][0][(size_t)tid * 8]);
                async16(&Kh[(size_t)(kn + srow + 32) * Dd + scs], &KV[cur ^ 1][0][(size_t)tid * 8 + 2048]);
                async16(&Vh[(size_t)srow * Ll + kn + scs],        &KV[cur ^ 1][1][(size_t)tid * 8]);
                async16(&Vh[(size_t)(srow + 32) * Ll + kn + scs], &KV[cur ^ 1][1][(size_t)tid * 8 + 2048]);
            }

            if (kt <= dtile) {   // wave-uniform (past-diag waves skip)
                const bf16* Ks = &KV[cur][0][0];
                const bf16* Vs = &KV[cur][1][0];
                const bool dg = (kt == dtile);

#pragma unroll
                for (int i = 0; i < 2; i++) {
                    const bool skip0 = dg && (i == 1);   // g=0: upper half fully masked

                    // K frags for this 32-k half (shared by both q-groups)
                    bf16x8 kf[4];
#pragma unroll
                    for (int s = 0; s < 4; s++)
                        kf[s] = *(const bf16x8*)
                            &Ks[(32 * i + l31) * 64 + (((2 * s + hb) ^ sw7) * 8)];

                    // St^T[k = 32i + koff][q], koff = (r&3)+8*(r>>2)+4*hb
                    f32x16 St0 = {}, St1 = {};
#pragma unroll
                    for (int s = 0; s < 4; s++) {
                        if (!skip0) St0 = MFMA32(kf[s], qf[0][s], St0);
                        St1 = MFMA32(kf[s], qf[1][s], St1);
                    }

                    const bool m0 = dg && (i == 0);   // g=0 triangular half
                    const bool m1 = dg && (i == 1);   // g=1 triangular half

                    {   // s = 0 (k16-block 32i + 0)
                        const int c0 = 4 * i + 0 + hb;
                        bf16x8 v0 = *(const bf16x8*)&Vs[l31 * 64 + ((c0 ^ sw7) * 8)];
                        bf16x8 v1 = *(const bf16x8*)&Vs[(32 + l31) * 64 + ((c0 ^ sw7) * 8)];
                        if (!skip0) {
                            bf16x8 pu = packP<0>(St0, m0, hb, l31, La0);
                            O00 = MFMA32(pu, v0, O00);
                            O01 = MFMA32(pu, v1, O01);
                        }
                        {
                            bf16x8 pu = packP<0>(St1, m1, hb, l31, La1);
                            O10 = MFMA32(pu, v0, O10);
                            O11 = MFMA32(pu, v1, O11);
                        }
                    }
                    {   // s = 1 (k16-block 32i + 16)
                        const int c0 = 4 * i + 2 + hb;
                        bf16x8 v0 = *(const bf16x8*)&Vs[l31 * 64 + ((c0 ^ sw7) * 8)];
                        bf16x8 v1 = *(const bf16x8*)&Vs[(32 + l31) * 64 + ((c0 ^ sw7) * 8)];
                        if (!skip0) {
                            bf16x8 pu = packP<1>(St0, m0, hb, l31, La0);
                            O00 = MFMA32(pu, v0, O00);
                            O01 = MFMA32(pu, v1, O01);
                        }
                        {
                            bf16x8 pu = packP<1>(St1, m1, hb, l31, La1);
                            O10 = MFMA32(pu, v0, O10);
                            O11 = MFMA32(pu, v1, O11);
                        }
                    }
                }
            }

            __syncthreads();   // single barrier: drains prefetch asyncs + flips buffers
        }

        // ---- epilogue: L via LDS half-partials per group (same-wave DS is
        // in-order). Lanes l31 / l31+32 hold the two halves of row l31 in
        // each group. Normalize in O-row layout and store AO[n][l][c]. ----
        {
            Lsc[wv][0][hb * 32 + l31] = La0;
            Lsc[wv][1][hb * 32 + l31] = La1;
            const float t0 = Lsc[wv][0][l31] + Lsc[wv][0][32 + l31];
            const float t1 = Lsc[wv][1][l31] + Lsc[wv][1][32 + l31];
            Lsc[wv][0][l31] = t0;   // both hb write same value
            Lsc[wv][1][l31] = t1;

            const size_t aobase = (size_t)n * Ll * Cc + (size_t)h * 64;
#pragma unroll
            for (int g = 0; g < 2; g++)
#pragma unroll
                for (int r = 0; r < 16; r++) {
                    const int qr = (r & 3) + 8 * (r >> 2) + 4 * hb;
                    const float inv = 1.0f / Lsc[wv][g][qr];
                    const size_t row = aobase + (size_t)(qbase + 32 * g + qr) * Cc;
                    const float o0 = (g == 0) ? O00[r] : O10[r];
                    const float o1 = (g == 0) ? O01[r] : O11[r];
                    AO[row + l31]      = (bf16)(o0 * inv);
                    AO[row + 32 + l31] = (bf16)(o1 * inv);
                }
        }
    }
}

// ---------------------------------------------------------------------------
// Output GEMM (m97 structure, unchanged), fp32 out + bias.
// ---------------------------------------------------------------------------
__global__ __launch_bounds__(256) void out_gemm(
    const bf16* __restrict__ AO, const bf16* __restrict__ Wb,
    const float* __restrict__ bo, float* __restrict__ out)
{
    const int lt = blockIdx.x, ot = blockIdx.y, n = blockIdx.z;

    __shared__ bf16 Ws[128 * 64];
    __shared__ bf16 Bs[128 * 64];

    const int tid = threadIdx.x;
    const int lane = tid & 63, wv = tid >> 6;
    const int m = lane & 15, quad = lane >> 4;
    const int rh = wv & 1, ch = wv >> 1;

    const bf16* __restrict__ W = Wb + 3 * WSZ + (size_t)ot * 128 * Cc;
    const bf16* __restrict__ B = AO + (size_t)(n * Ll + lt * 128) * Cc;

    int srow[4], scol[4];
#pragma unroll
    for (int i = 0; i < 4; i++) {
        int q = i * 256 + tid;
        srow[i] = q >> 3;
        scol[i] = ((q ^ (q >> 3)) & 7) * 8;
    }

    f32x4 acc[4][4] = {};

    for (int c0 = 0; c0 < Cc; c0 += 64) {
#pragma unroll
        for (int i = 0; i < 4; i++)
            async16(&W[(size_t)srow[i] * Cc + c0 + scol[i]], &Ws[(i * 256 + tid) * 8]);
#pragma unroll
        for (int i = 0; i < 4; i++)
            async16(&B[(size_t)srow[i] * Cc + c0 + scol[i]], &Bs[(i * 256 + tid) * 8]);
        __syncthreads();

#pragma unroll
        for (int kk = 0; kk < 2; kk++) {
            const int sw = (((kk * 4 + quad) ^ (m & 7)) * 8);
            bf16x8 af[4], bfr[4];
#pragma unroll
            for (int t = 0; t < 4; t++)
                af[t] = *(const bf16x8*)&Ws[(rh * 64 + t * 16 + m) * 64 + sw];
#pragma unroll
            for (int u = 0; u < 4; u++)
                bfr[u] = *(const bf16x8*)&Bs[(ch * 64 + u * 16 + m) * 64 + sw];
#pragma unroll
            for (int t = 0; t < 4; t++)
#pragma unroll
                for (int u = 0; u < 4; u++)
                    acc[t][u] = MFMA(af[t], bfr[u], acc[t][u]);
        }
        __syncthreads();
    }

#pragma unroll
    for (int t = 0; t < 4; t++) {
        const int ob = ot * 128 + rh * 64 + t * 16 + quad * 4;
#pragma unroll
        for (int r = 0; r < 4; r++) {
            const int o = ob + r;
            const float b = bo[o];
            float* base = out + ((size_t)n * Cc + o) * Ll + lt * 128 + ch * 64;
#pragma unroll
            for (int u = 0; u < 4; u++)
                base[u * 16 + m] = acc[t][u][r] + b;
        }
    }
}

// ---------------------------------------------------------------------------
extern "C" void kernel_launch(void* const* d_in, const int* in_sizes, int n_in,
                              void* d_out, int out_size, void* d_ws, size_t ws_size,
                              hipStream_t stream)
{
    const float* x  = (const float*)d_in[0];
    const float* Wq = (const float*)d_in[1];
    const float* Wk = (const float*)d_in[2];
    const float* Wv = (const float*)d_in[3];
    const float* Wo = (const float*)d_in[4];
    const float* bo = (const float*)d_in[5];
    float* out = (float*)d_out;

    bf16* ws = (bf16*)d_ws;
    bf16* xT = ws;                        // [n][l][c]
    bf16* Wb = xT + NCL;                  // 4 x 512x512
    bf16* Qt = Wb + 4 * WSZ;              // [n][h][l][d]  (pre-scaled)
    bf16* Kt = Qt + NCL;                  // [n][h][l][d]
    bf16* Vb = Kt + NCL;                  // [n][h][d][l]
    bf16* AO = Vb + NCL;                  // [n][l][c]

    prep_kernel<<<dim3(32, 8, Nn + 1), 256, 0, stream>>>(x, Wq, Wk, Wv, Wo, xT, Wb);
    qkv_gemm<<<dim3(16, 12, Nn), 256, 0, stream>>>(xT, Wb, Qt, Kt, Vb);
    attn_mfma<<<dim3(Hh, 4, Nn), 256, 0, stream>>>(Qt, Kt, Vb, AO);
    out_gemm<<<dim3(16, 4, Nn), 256, 0, stream>>>(AO, Wb, bo, out);
}

// Round 13
// 207.924 us; speedup vs baseline: 1.0091x; 1.0091x over previous
//
#include <hip/hip_runtime.h>
#include <math.h>

typedef __bf16 bf16;
typedef __attribute__((ext_vector_type(8))) __bf16 bf16x8;
typedef __attribute__((ext_vector_type(4))) float f32x4;
typedef __attribute__((ext_vector_type(16))) float f32x16;
typedef unsigned short u16;
typedef unsigned int u32;

constexpr int Nn = 8, Cc = 512, Ll = 2048, Hh = 8, Dd = 64;
constexpr float kScale = 0.044194173824159216f;           // 512^-0.5
constexpr float kQexp2 = kScale * 1.44269504088896341f;   // fold log2(e) into Q
constexpr size_t NCL = (size_t)Nn * Cc * Ll;
constexpr size_t WSZ = (size_t)Cc * Cc;

static __device__ __forceinline__ u16 bfbits(bf16 v) {
    union { bf16 b; u16 u; } x; x.b = v; return x.u;
}
static __device__ __forceinline__ float fexp2(float x) {
#if __has_builtin(__builtin_amdgcn_exp2f)
    return __builtin_amdgcn_exp2f(x);
#else
    return exp2f(x);
#endif
}

#define MFMA(a, b, c) __builtin_amdgcn_mfma_f32_16x16x32_bf16((a), (b), (c), 0, 0, 0)
#define MFMA32(a, b, c) __builtin_amdgcn_mfma_f32_32x32x16_bf16((a), (b), (c), 0, 0, 0)

static __device__ __forceinline__ void async16(const bf16* g, bf16* l) {
    __builtin_amdgcn_global_load_lds(
        (const __attribute__((address_space(1))) void*)g,
        (__attribute__((address_space(3))) void*)l, 16, 0, 0);
}

// pack two f32 -> one dword of 2 bf16 (RNE), lo in low half
static __device__ __forceinline__ u32 cvtpk(float lo, float hi) {
    u32 d;
    asm("v_cvt_pk_bf16_f32 %0, %1, %2" : "=v"(d) : "v"(lo), "v"(hi));
    return d;
}
// v_permlane32_swap_b32 vdst, vsrc: vdst lanes[32:63] <-> vsrc lanes[0:31]
//   => dst_new = [dst_lo | src_lo], src_new = [dst_hi | src_hi]
// NOTE: only safe with DISTINCT-valued operands (regalloc can coalesce
// equal-valued registers into one -> swap_b32 v,v destroys a half; this was
// the epilogue-L NaN root cause in v11/v12). All uses below have distinct
// cvtpk results as operands (the form v10/v13b/v16 compiled + passed with).
static __device__ __forceinline__ void swap32(u32& d, u32& s) {
    asm volatile("v_permlane32_swap_b32 %0, %1" : "+v"(d), "+v"(s));
}

// softmax a 16-wide St half (k16-block S within the 32-half), build PV A-frag.
// St[r]: S[k = 16*S + (r&3)+8*(r>>2)+4*hb][q = l31]; msk: triangular kc>l31.
// (kc formula includes the 16*S offset via 8*(r>>2).)
template<int S>
static __device__ __forceinline__ bf16x8 packP(const f32x16 St, bool msk,
                                               int hb, int l31, float& La)
{
    float p[8];
#pragma unroll
    for (int j = 0; j < 8; j++) {
        const int r = S * 8 + j;
        float pv = fexp2(St[r]);
        if (msk) {
            const int kc = (r & 3) + 8 * (r >> 2) + 4 * hb;
            if (kc > l31) pv = 0.f;
        }
        p[j] = pv;
    }
    La += ((p[0] + p[1]) + (p[2] + p[3])) + ((p[4] + p[5]) + (p[6] + p[7]));
    // lane values after cvtpk (lo-lane / hi-lane):
    //   A: k(0,1)/k(4,5)  B: k(2,3)/k(6,7)  C: k(8,9)/k(12,13) D: k(10,11)/k(14,15)
    u32 A = cvtpk(p[0], p[1]);
    u32 B = cvtpk(p[2], p[3]);
    u32 C = cvtpk(p[4], p[5]);
    u32 D = cvtpk(p[6], p[7]);
    // dst_hi <-> src_lo: A=[A_lo|C_lo], C=[A_hi|C_hi]; B=[B_lo|D_lo], D=[B_hi|D_hi]
    // -> lo-lane frag = k(0..7), hi-lane frag = k(8..15)  (MFMA32 A-layout)
    swap32(A, C);
    swap32(B, D);
    union { u32 w[4]; bf16x8 v; } pu;
    pu.w[0] = A; pu.w[1] = B; pu.w[2] = C; pu.w[3] = D;
    return pu.v;
}

// ---------------------------------------------------------------------------
// prep: z<8 -> x [n][c][l] fp32 -> xT [n][l][c] bf16 (64x64 tiles via LDS);
//       z==8 -> weights fp32 -> bf16.  grid (32, 8, 9), block 256.
// ---------------------------------------------------------------------------
__global__ __launch_bounds__(256) void prep_kernel(
    const float* __restrict__ x,
    const float* __restrict__ Wq, const float* __restrict__ Wk,
    const float* __restrict__ Wv, const float* __restrict__ Wo,
    bf16* __restrict__ xT, bf16* __restrict__ Wb)
{
    const int tid = threadIdx.x;
    if (blockIdx.z == Nn) {
        int gid = (blockIdx.y * 32 + blockIdx.x) * 256 + tid;   // 0..65535
        int w = gid >> 14;
        int o = (gid & 16383) * 4;                              // float4 base
        const float* src = (w == 0) ? Wq : (w == 1) ? Wk : (w == 2) ? Wv : Wo;
        bf16* dst = Wb + (size_t)w * WSZ;
#pragma unroll
        for (int j = 0; j < 4; j++) {
            float4 v = ((const float4*)src)[o + j];
            ushort4 u;
            u.x = bfbits((bf16)v.x); u.y = bfbits((bf16)v.y);
            u.z = bfbits((bf16)v.z); u.w = bfbits((bf16)v.w);
            *(ushort4*)(dst + (size_t)(o + j) * 4) = u;
        }
        return;
    }

    __shared__ bf16 Ts[64][72];
    const int lt = blockIdx.x, ct = blockIdx.y, n = blockIdx.z;

    const int cr = tid >> 2, l0 = (tid & 3) * 16;
    const float* src = x + ((size_t)(n * Cc + ct * 64 + cr)) * Ll + lt * 64 + l0;
#pragma unroll
    for (int i = 0; i < 4; i++) {
        float4 v = *(const float4*)(src + i * 4);
        Ts[l0 + i * 4 + 0][cr] = (bf16)v.x;
        Ts[l0 + i * 4 + 1][cr] = (bf16)v.y;
        Ts[l0 + i * 4 + 2][cr] = (bf16)v.z;
        Ts[l0 + i * 4 + 3][cr] = (bf16)v.w;
    }
    __syncthreads();

    const int lr = tid >> 2, c0 = (tid & 3) * 16;
    bf16* dst = xT + ((size_t)(n * Ll + lt * 64 + lr)) * Cc + ct * 64 + c0;
    *(bf16x8*)(dst)     = *(const bf16x8*)&Ts[lr][c0];
    *(bf16x8*)(dst + 8) = *(const bf16x8*)&Ts[lr][c0 + 8];
}

// ---------------------------------------------------------------------------
// QKV GEMM (m97 structure, unchanged). Q pre-scaled by kScale*log2e.
// ---------------------------------------------------------------------------
__global__ __launch_bounds__(256) void qkv_gemm(
    const bf16* __restrict__ xT, const bf16* __restrict__ Wb,
    bf16* __restrict__ Qt, bf16* __restrict__ Kt, bf16* __restrict__ Vb)
{
    const int lt = blockIdx.x, ow = blockIdx.y, n = blockIdx.z;
    const int widx = ow >> 2, otile = ow & 3;

    __shared__ bf16 Xs[128 * 64];
    __shared__ bf16 Ws[128 * 64];

    const int tid = threadIdx.x;
    const int lane = tid & 63, wv = tid >> 6;
    const int m = lane & 15, quad = lane >> 4;
    const int rh = wv & 1, ch = wv >> 1;

    const bf16* __restrict__ W = Wb + (size_t)widx * WSZ + (size_t)otile * 128 * Cc;
    const bf16* __restrict__ X = xT + (size_t)(n * Ll + lt * 128) * Cc;

    int srow[4], scol[4];
#pragma unroll
    for (int i = 0; i < 4; i++) {
        int q = i * 256 + tid;
        srow[i] = q >> 3;
        scol[i] = ((q ^ (q >> 3)) & 7) * 8;
    }

    f32x4 acc[4][4] = {};

    for (int c0 = 0; c0 < Cc; c0 += 64) {
#pragma unroll
        for (int i = 0; i < 4; i++)
            async16(&X[(size_t)srow[i] * Cc + c0 + scol[i]], &Xs[(i * 256 + tid) * 8]);
#pragma unroll
        for (int i = 0; i < 4; i++)
            async16(&W[(size_t)srow[i] * Cc + c0 + scol[i]], &Ws[(i * 256 + tid) * 8]);
        __syncthreads();

        const bf16* TA = (widx < 2) ? Xs : Ws;
        const bf16* TB = (widx < 2) ? Ws : Xs;
#pragma unroll
        for (int kk = 0; kk < 2; kk++) {
            const int sw = (((kk * 4 + quad) ^ (m & 7)) * 8);
            bf16x8 af[4], bfr[4];
#pragma unroll
            for (int t = 0; t < 4; t++)
                af[t] = *(const bf16x8*)&TA[(rh * 64 + t * 16 + m) * 64 + sw];
#pragma unroll
            for (int u = 0; u < 4; u++)
                bfr[u] = *(const bf16x8*)&TB[(ch * 64 + u * 16 + m) * 64 + sw];
#pragma unroll
            for (int t = 0; t < 4; t++)
#pragma unroll
                for (int u = 0; u < 4; u++)
                    acc[t][u] = MFMA(af[t], bfr[u], acc[t][u]);
        }
        __syncthreads();
    }

    if (widx < 2) {
        const float fq = (widx == 0) ? kQexp2 : 1.0f;
        bf16* __restrict__ OUT = (widx == 0) ? Qt : Kt;
#pragma unroll
        for (int u = 0; u < 4; u++) {
            const int o = otile * 128 + ch * 64 + u * 16 + m;
            const int h = o >> 6, d = o & 63;
            bf16* base = OUT + (size_t)(n * Hh + h) * Ll * Dd + d;
#pragma unroll
            for (int t = 0; t < 4; t++) {
                const int l0 = lt * 128 + rh * 64 + t * 16 + quad * 4;
#pragma unroll
                for (int r = 0; r < 4; r++)
                    base[(size_t)(l0 + r) * Dd] = (bf16)(acc[t][u][r] * fq);
            }
        }
    } else {
#pragma unroll
        for (int t = 0; t < 4; t++) {
            const int ob = otile * 128 + rh * 64 + t * 16 + quad * 4;
#pragma unroll
            for (int r = 0; r < 4; r++) {
                const int oo = ob + r, h = oo >> 6, d = oo & 63;
                bf16* base = Vb + ((size_t)(n * Hh + h) * Dd + d) * Ll;
#pragma unroll
                for (int u = 0; u < 4; u++)
                    base[lt * 128 + ch * 64 + u * 16 + m] = (bf16)acc[t][u][r];
            }
        }
    }
}

// ---------------------------------------------------------------------------
// Causal attention v17 = v16's verified per-wave body (64 q/wave fold: two
// 32-q groups share every K/V fragment read) at RESTORED 2 waves/SIMD:
// one 512-thread block per CU, 8 waves x 64q = 512-row supertile, grid
// (h, 4, n) = 256 blocks, ALL resident. v16's regression was concurrency
// (1 wave/SIMD exposed the serial chain: wall 5100 cy/iter vs busy ~2550);
// v13b showed 2 waves/SIMD hides stalls (wall 2016 vs latency 4030).
// Makespan = st=3 blocks' 32 iters; per-CU worst work (256 wave-iters) is
// BELOW v13b's uniform 272. Staging halves: 512 threads cover a 64x64 tile
// with 1 async16 per K and per V. LDS 36 KB. Causal: dtile = 8*st + wv,
// qbase = st*512 + wv*64; in-tile g/i mask algebra is v16's verbatim.
// ---------------------------------------------------------------------------
__global__ __launch_bounds__(512, 1) void attn_mfma(
    const bf16* __restrict__ Qt, const bf16* __restrict__ Kt,
    const bf16* __restrict__ Vb, bf16* __restrict__ AO)
{
    const int h  = blockIdx.x;
    const int st = blockIdx.y;   // supertile 0..3 (512 q-rows each)
    const int n  = blockIdx.z;

    __shared__ bf16 KV[2][2][64 * 64];   // [buf][K=0 / V^T=1] 32 KB
    __shared__ float Lsc[8][2][64];      // per-wave, per-group row-sum halves

    const int tid = threadIdx.x;              // 0..511
    const int lane = tid & 63, wv = tid >> 6; // 8 waves
    const int l31 = lane & 31, hb = lane >> 5;
    const int sw7 = l31 & 7;

    const size_t bnh = (size_t)(n * Hh + h) * Ll * Dd;
    const bf16* __restrict__ Qh = Qt + bnh;
    const bf16* __restrict__ Kh = Kt + bnh;
    const bf16* __restrict__ Vh = Vb + bnh;

    const int srow = tid >> 3;                        // 0..63 (full tile)
    const int scs  = (((tid & 7) ^ (srow & 7)) * 8);  // swizzled global chunk

    const int nk = 8 * st + 8;
    const int dtile = 8 * st + wv;          // this wave's diagonal k-tile
    const int qbase = st * 512 + wv * 64;

    // Q as B-fragments: lane holds Q[q=qbase+32g+l31][d = s*16 + hb*8 + j]
    bf16x8 qf[2][4];
#pragma unroll
    for (int g = 0; g < 2; g++)
#pragma unroll
        for (int s = 0; s < 4; s++)
            qf[g][s] = *(const bf16x8*)
                &Qh[(size_t)(qbase + 32 * g + l31) * Dd + s * 16 + hb * 8];

    f32x16 O00 = {}, O01 = {}, O10 = {}, O11 = {};   // O[g][dv-half]
    float La0 = 0.f, La1 = 0.f;

    // stage tile 0 -> buf 0 (512 threads cover 64x64: 1 call per K / V)
    async16(&Kh[(size_t)srow * Dd + scs], &KV[0][0][(size_t)tid * 8]);
    async16(&Vh[(size_t)srow * Ll + scs], &KV[0][1][(size_t)tid * 8]);
    __syncthreads();   // drains asyncs

    for (int kt = 0; kt < nk; kt++) {
        const int cur = kt & 1;

        if (kt + 1 < nk) {   // prefetch next tile into the other buffer
            const int kn = (kt + 1) * 64;
            async16(&Kh[(size_t)(kn + srow) * Dd + scs], &KV[cur ^ 1][0][(size_t)tid * 8]);
            async16(&Vh[(size_t)srow * Ll + kn + scs],   &KV[cur ^ 1][1][(size_t)tid * 8]);
        }

        if (kt <= dtile) {   // wave-uniform (past-diag waves skip)
            const bf16* Ks = &KV[cur][0][0];
            const bf16* Vs = &KV[cur][1][0];
            const bool dg = (kt == dtile);

#pragma unroll
            for (int i = 0; i < 2; i++) {
                const bool skip0 = dg && (i == 1);   // g=0: upper half fully masked

                // K frags for this 32-k half (shared by both q-groups)
                bf16x8 kf[4];
#pragma unroll
                for (int s = 0; s < 4; s++)
                    kf[s] = *(const bf16x8*)
                        &Ks[(32 * i + l31) * 64 + (((2 * s + hb) ^ sw7) * 8)];

                // St^T[k = 32i + koff][q], koff = (r&3)+8*(r>>2)+4*hb
                f32x16 St0 = {}, St1 = {};
#pragma unroll
                for (int s = 0; s < 4; s++) {
                    if (!skip0) St0 = MFMA32(kf[s], qf[0][s], St0);
                    St1 = MFMA32(kf[s], qf[1][s], St1);
                }

                const bool m0 = dg && (i == 0);   // g=0 triangular half
                const bool m1 = dg && (i == 1);   // g=1 triangular half

                {   // s = 0 (k16-block 32i + 0)
                    const int c0 = 4 * i + 0 + hb;
                    bf16x8 v0 = *(const bf16x8*)&Vs[l31 * 64 + ((c0 ^ sw7) * 8)];
                    bf16x8 v1 = *(const bf16x8*)&Vs[(32 + l31) * 64 + ((c0 ^ sw7) * 8)];
                    if (!skip0) {
                        bf16x8 pu = packP<0>(St0, m0, hb, l31, La0);
                        O00 = MFMA32(pu, v0, O00);
                        O01 = MFMA32(pu, v1, O01);
                    }
                    {
                        bf16x8 pu = packP<0>(St1, m1, hb, l31, La1);
                        O10 = MFMA32(pu, v0, O10);
                        O11 = MFMA32(pu, v1, O11);
                    }
                }
                {   // s = 1 (k16-block 32i + 16)
                    const int c0 = 4 * i + 2 + hb;
                    bf16x8 v0 = *(const bf16x8*)&Vs[l31 * 64 + ((c0 ^ sw7) * 8)];
                    bf16x8 v1 = *(const bf16x8*)&Vs[(32 + l31) * 64 + ((c0 ^ sw7) * 8)];
                    if (!skip0) {
                        bf16x8 pu = packP<1>(St0, m0, hb, l31, La0);
                        O00 = MFMA32(pu, v0, O00);
                        O01 = MFMA32(pu, v1, O01);
                    }
                    {
                        bf16x8 pu = packP<1>(St1, m1, hb, l31, La1);
                        O10 = MFMA32(pu, v0, O10);
                        O11 = MFMA32(pu, v1, O11);
                    }
                }
            }
        }

        __syncthreads();   // single barrier: drains prefetch asyncs + flips buffers
    }

    // ---- epilogue: L via LDS half-partials per group (same-wave DS is
    // in-order). Lanes l31 / l31+32 hold the two halves of row l31 in
    // each group. Normalize in O-row layout and store AO[n][l][c]. ----
    {
        Lsc[wv][0][hb * 32 + l31] = La0;
        Lsc[wv][1][hb * 32 + l31] = La1;
        const float t0 = Lsc[wv][0][l31] + Lsc[wv][0][32 + l31];
        const float t1 = Lsc[wv][1][l31] + Lsc[wv][1][32 + l31];
        Lsc[wv][0][l31] = t0;   // both hb write same value
        Lsc[wv][1][l31] = t1;

        const size_t aobase = (size_t)n * Ll * Cc + (size_t)h * 64;
#pragma unroll
        for (int g = 0; g < 2; g++)
#pragma unroll
            for (int r = 0; r < 16; r++) {
                const int qr = (r & 3) + 8 * (r >> 2) + 4 * hb;
                const float inv = 1.0f / Lsc[wv][g][qr];
                const size_t row = aobase + (size_t)(qbase + 32 * g + qr) * Cc;
                const float o0 = (g == 0) ? O00[r] : O10[r];
                const float o1 = (g == 0) ? O01[r] : O11[r];
                AO[row + l31]      = (bf16)(o0 * inv);
                AO[row + 32 + l31] = (bf16)(o1 * inv);
            }
    }
}

// ---------------------------------------------------------------------------
// Output GEMM (m97 structure, unchanged), fp32 out + bias.
// ---------------------------------------------------------------------------
__global__ __launch_bounds__(256) void out_gemm(
    const bf16* __restrict__ AO, const bf16* __restrict__ Wb,
    const float* __restrict__ bo, float* __restrict__ out)
{
    const int lt = blockIdx.x, ot = blockIdx.y, n = blockIdx.z;

    __shared__ bf16 Ws[128 * 64];
    __shared__ bf16 Bs[128 * 64];

    const int tid = threadIdx.x;
    const int lane = tid & 63, wv = tid >> 6;
    const int m = lane & 15, quad = lane >> 4;
    const int rh = wv & 1, ch = wv >> 1;

    const bf16* __restrict__ W = Wb + 3 * WSZ + (size_t)ot * 128 * Cc;
    const bf16* __restrict__ B = AO + (size_t)(n * Ll + lt * 128) * Cc;

    int srow[4], scol[4];
#pragma unroll
    for (int i = 0; i < 4; i++) {
        int q = i * 256 + tid;
        srow[i] = q >> 3;
        scol[i] = ((q ^ (q >> 3)) & 7) * 8;
    }

    f32x4 acc[4][4] = {};

    for (int c0 = 0; c0 < Cc; c0 += 64) {
#pragma unroll
        for (int i = 0; i < 4; i++)
            async16(&W[(size_t)srow[i] * Cc + c0 + scol[i]], &Ws[(i * 256 + tid) * 8]);
#pragma unroll
        for (int i = 0; i < 4; i++)
            async16(&B[(size_t)srow[i] * Cc + c0 + scol[i]], &Bs[(i * 256 + tid) * 8]);
        __syncthreads();

#pragma unroll
        for (int kk = 0; kk < 2; kk++) {
            const int sw = (((kk * 4 + quad) ^ (m & 7)) * 8);
            bf16x8 af[4], bfr[4];
#pragma unroll
            for (int t = 0; t < 4; t++)
                af[t] = *(const bf16x8*)&Ws[(rh * 64 + t * 16 + m) * 64 + sw];
#pragma unroll
            for (int u = 0; u < 4; u++)
                bfr[u] = *(const bf16x8*)&Bs[(ch * 64 + u * 16 + m) * 64 + sw];
#pragma unroll
            for (int t = 0; t < 4; t++)
#pragma unroll
                for (int u = 0; u < 4; u++)
                    acc[t][u] = MFMA(af[t], bfr[u], acc[t][u]);
        }
        __syncthreads();
    }

#pragma unroll
    for (int t = 0; t < 4; t++) {
        const int ob = ot * 128 + rh * 64 + t * 16 + quad * 4;
#pragma unroll
        for (int r = 0; r < 4; r++) {
            const int o = ob + r;
            const float b = bo[o];
            float* base = out + ((size_t)n * Cc + o) * Ll + lt * 128 + ch * 64;
#pragma unroll
            for (int u = 0; u < 4; u++)
                base[u * 16 + m] = acc[t][u][r] + b;
        }
    }
}

// ---------------------------------------------------------------------------
extern "C" void kernel_launch(void* const* d_in, const int* in_sizes, int n_in,
                              void* d_out, int out_size, void* d_ws, size_t ws_size,
                              hipStream_t stream)
{
    const float* x  = (const float*)d_in[0];
    const float* Wq = (const float*)d_in[1];
    const float* Wk = (const float*)d_in[2];
    const float* Wv = (const float*)d_in[3];
    const float* Wo = (const float*)d_in[4];
    const float* bo = (const float*)d_in[5];
    float* out = (float*)d_out;

    bf16* ws = (bf16*)d_ws;
    bf16* xT = ws;                        // [n][l][c]
    bf16* Wb = xT + NCL;                  // 4 x 512x512
    bf16* Qt = Wb + 4 * WSZ;              // [n][h][l][d]  (pre-scaled)
    bf16* Kt = Qt + NCL;                  // [n][h][l][d]
    bf16* Vb = Kt + NCL;                  // [n][h][d][l]
    bf16* AO = Vb + NCL;                  // [n][l][c]

    prep_kernel<<<dim3(32, 8, Nn + 1), 256, 0, stream>>>(x, Wq, Wk, Wv, Wo, xT, Wb);
    qkv_gemm<<<dim3(16, 12, Nn), 256, 0, stream>>>(xT, Wb, Qt, Kt, Vb);
    attn_mfma<<<dim3(Hh, 4, Nn), 512, 0, stream>>>(Qt, Kt, Vb, AO);
    out_gemm<<<dim3(16, 4, Nn), 256, 0, stream>>>(AO, Wb, bo, out);
}

// Round 14
// 193.428 us; speedup vs baseline: 1.0847x; 1.0749x over previous
//
#include <hip/hip_runtime.h>
#include <math.h>

typedef __bf16 bf16;
typedef __attribute__((ext_vector_type(8))) __bf16 bf16x8;
typedef __attribute__((ext_vector_type(4))) float f32x4;
typedef __attribute__((ext_vector_type(16))) float f32x16;
typedef unsigned short u16;
typedef unsigned int u32;

constexpr int Nn = 8, Cc = 512, Ll = 2048, Hh = 8, Dd = 64;
constexpr float kScale = 0.044194173824159216f;           // 512^-0.5
constexpr float kQexp2 = kScale * 1.44269504088896341f;   // fold log2(e) into Q
constexpr size_t NCL = (size_t)Nn * Cc * Ll;
constexpr size_t WSZ = (size_t)Cc * Cc;

static __device__ __forceinline__ u16 bfbits(bf16 v) {
    union { bf16 b; u16 u; } x; x.b = v; return x.u;
}
static __device__ __forceinline__ float fexp2(float x) {
#if __has_builtin(__builtin_amdgcn_exp2f)
    return __builtin_amdgcn_exp2f(x);
#else
    return exp2f(x);
#endif
}

#define MFMA(a, b, c) __builtin_amdgcn_mfma_f32_16x16x32_bf16((a), (b), (c), 0, 0, 0)
#define MFMA32(a, b, c) __builtin_amdgcn_mfma_f32_32x32x16_bf16((a), (b), (c), 0, 0, 0)

static __device__ __forceinline__ void async16(const bf16* g, bf16* l) {
    __builtin_amdgcn_global_load_lds(
        (const __attribute__((address_space(1))) void*)g,
        (__attribute__((address_space(3))) void*)l, 16, 0, 0);
}

// pack two f32 -> one dword of 2 bf16 (RNE), lo in low half
static __device__ __forceinline__ u32 cvtpk(float lo, float hi) {
    u32 d;
    asm("v_cvt_pk_bf16_f32 %0, %1, %2" : "=v"(d) : "v"(lo), "v"(hi));
    return d;
}
// v_permlane32_swap_b32 vdst, vsrc: vdst lanes[32:63] <-> vsrc lanes[0:31]
//   => dst_new = [dst_lo | src_lo], src_new = [dst_hi | src_hi]
// NOTE: only safe with DISTINCT-valued operands (regalloc can coalesce
// equal-valued registers into one -> swap_b32 v,v destroys a half; this was
// the epilogue-L NaN root cause in v11/v12). All uses below have distinct
// cvtpk results as operands (the form v10/v13b compiled + passed with).
static __device__ __forceinline__ void swap32(u32& d, u32& s) {
    asm volatile("v_permlane32_swap_b32 %0, %1" : "+v"(d), "+v"(s));
}

// ---------------------------------------------------------------------------
// prep: z<8 -> x [n][c][l] fp32 -> xT [n][l][c] bf16 (64x64 tiles via LDS);
//       z==8 -> weights fp32 -> bf16.  grid (32, 8, 9), block 256.
// ---------------------------------------------------------------------------
__global__ __launch_bounds__(256) void prep_kernel(
    const float* __restrict__ x,
    const float* __restrict__ Wq, const float* __restrict__ Wk,
    const float* __restrict__ Wv, const float* __restrict__ Wo,
    bf16* __restrict__ xT, bf16* __restrict__ Wb)
{
    const int tid = threadIdx.x;
    if (blockIdx.z == Nn) {
        int gid = (blockIdx.y * 32 + blockIdx.x) * 256 + tid;   // 0..65535
        int w = gid >> 14;
        int o = (gid & 16383) * 4;                              // float4 base
        const float* src = (w == 0) ? Wq : (w == 1) ? Wk : (w == 2) ? Wv : Wo;
        bf16* dst = Wb + (size_t)w * WSZ;
#pragma unroll
        for (int j = 0; j < 4; j++) {
            float4 v = ((const float4*)src)[o + j];
            ushort4 u;
            u.x = bfbits((bf16)v.x); u.y = bfbits((bf16)v.y);
            u.z = bfbits((bf16)v.z); u.w = bfbits((bf16)v.w);
            *(ushort4*)(dst + (size_t)(o + j) * 4) = u;
        }
        return;
    }

    __shared__ bf16 Ts[64][72];
    const int lt = blockIdx.x, ct = blockIdx.y, n = blockIdx.z;

    const int cr = tid >> 2, l0 = (tid & 3) * 16;
    const float* src = x + ((size_t)(n * Cc + ct * 64 + cr)) * Ll + lt * 64 + l0;
#pragma unroll
    for (int i = 0; i < 4; i++) {
        float4 v = *(const float4*)(src + i * 4);
        Ts[l0 + i * 4 + 0][cr] = (bf16)v.x;
        Ts[l0 + i * 4 + 1][cr] = (bf16)v.y;
        Ts[l0 + i * 4 + 2][cr] = (bf16)v.z;
        Ts[l0 + i * 4 + 3][cr] = (bf16)v.w;
    }
    __syncthreads();

    const int lr = tid >> 2, c0 = (tid & 3) * 16;
    bf16* dst = xT + ((size_t)(n * Ll + lt * 64 + lr)) * Cc + ct * 64 + c0;
    *(bf16x8*)(dst)     = *(const bf16x8*)&Ts[lr][c0];
    *(bf16x8*)(dst + 8) = *(const bf16x8*)&Ts[lr][c0 + 8];
}

// ---------------------------------------------------------------------------
// QKV GEMM (m97 structure, unchanged). Q pre-scaled by kScale*log2e.
// ---------------------------------------------------------------------------
__global__ __launch_bounds__(256) void qkv_gemm(
    const bf16* __restrict__ xT, const bf16* __restrict__ Wb,
    bf16* __restrict__ Qt, bf16* __restrict__ Kt, bf16* __restrict__ Vb)
{
    const int lt = blockIdx.x, ow = blockIdx.y, n = blockIdx.z;
    const int widx = ow >> 2, otile = ow & 3;

    __shared__ bf16 Xs[128 * 64];
    __shared__ bf16 Ws[128 * 64];

    const int tid = threadIdx.x;
    const int lane = tid & 63, wv = tid >> 6;
    const int m = lane & 15, quad = lane >> 4;
    const int rh = wv & 1, ch = wv >> 1;

    const bf16* __restrict__ W = Wb + (size_t)widx * WSZ + (size_t)otile * 128 * Cc;
    const bf16* __restrict__ X = xT + (size_t)(n * Ll + lt * 128) * Cc;

    int srow[4], scol[4];
#pragma unroll
    for (int i = 0; i < 4; i++) {
        int q = i * 256 + tid;
        srow[i] = q >> 3;
        scol[i] = ((q ^ (q >> 3)) & 7) * 8;
    }

    f32x4 acc[4][4] = {};

    for (int c0 = 0; c0 < Cc; c0 += 64) {
#pragma unroll
        for (int i = 0; i < 4; i++)
            async16(&X[(size_t)srow[i] * Cc + c0 + scol[i]], &Xs[(i * 256 + tid) * 8]);
#pragma unroll
        for (int i = 0; i < 4; i++)
            async16(&W[(size_t)srow[i] * Cc + c0 + scol[i]], &Ws[(i * 256 + tid) * 8]);
        __syncthreads();

        const bf16* TA = (widx < 2) ? Xs : Ws;
        const bf16* TB = (widx < 2) ? Ws : Xs;
#pragma unroll
        for (int kk = 0; kk < 2; kk++) {
            const int sw = (((kk * 4 + quad) ^ (m & 7)) * 8);
            bf16x8 af[4], bfr[4];
#pragma unroll
            for (int t = 0; t < 4; t++)
                af[t] = *(const bf16x8*)&TA[(rh * 64 + t * 16 + m) * 64 + sw];
#pragma unroll
            for (int u = 0; u < 4; u++)
                bfr[u] = *(const bf16x8*)&TB[(ch * 64 + u * 16 + m) * 64 + sw];
#pragma unroll
            for (int t = 0; t < 4; t++)
#pragma unroll
                for (int u = 0; u < 4; u++)
                    acc[t][u] = MFMA(af[t], bfr[u], acc[t][u]);
        }
        __syncthreads();
    }

    if (widx < 2) {
        const float fq = (widx == 0) ? kQexp2 : 1.0f;
        bf16* __restrict__ OUT = (widx == 0) ? Qt : Kt;
#pragma unroll
        for (int u = 0; u < 4; u++) {
            const int o = otile * 128 + ch * 64 + u * 16 + m;
            const int h = o >> 6, d = o & 63;
            bf16* base = OUT + (size_t)(n * Hh + h) * Ll * Dd + d;
#pragma unroll
            for (int t = 0; t < 4; t++) {
                const int l0 = lt * 128 + rh * 64 + t * 16 + quad * 4;
#pragma unroll
                for (int r = 0; r < 4; r++)
                    base[(size_t)(l0 + r) * Dd] = (bf16)(acc[t][u][r] * fq);
            }
        }
    } else {
#pragma unroll
        for (int t = 0; t < 4; t++) {
            const int ob = otile * 128 + rh * 64 + t * 16 + quad * 4;
#pragma unroll
            for (int r = 0; r < 4; r++) {
                const int oo = ob + r, h = oo >> 6, d = oo & 63;
                bf16* base = Vb + ((size_t)(n * Hh + h) * Dd + d) * Ll;
#pragma unroll
                for (int u = 0; u < 4; u++)
                    base[lt * 128 + ch * 64 + u * 16 + m] = (bf16)acc[t][u][r];
            }
        }
    }
}

// ---------------------------------------------------------------------------
// Causal attention v18 = v13b byte-identical compute/staging/epilogue, but
// TWO 64-k subtiles per barrier (128-wide k-step). v13b's wall was 34 iters
// x ~2016 cy where ~800 cy/iter is fixed barrier+drain overhead; processing
// 2 subtiles per barrier amortizes that to 17 iters. Zero new address
// algebra: LDS = KV[buf][h64][K/V][64*64], each subtile staged with v13b's
// exact 4-async16 pattern (kn = b*128 + h64*64) and computed with v13b's
// exact body (kt64 = 2b + h64; same dtile/mhalf/mask). Uniform pairing
// {jp,15-jp}: nk128 = st+1 -> 17 iters/block. LDS 66 KB -> 2 blocks/CU.
// Grid (h, 8, n) = 512 blocks, all resident.
// ---------------------------------------------------------------------------
__global__ __launch_bounds__(256, 4) void attn_mfma(
    const bf16* __restrict__ Qt, const bf16* __restrict__ Kt,
    const bf16* __restrict__ Vb, bf16* __restrict__ AO)
{
    const int h  = blockIdx.x;
    const int jp = blockIdx.y;   // 0..7 -> pair {jp, 15-jp}
    const int n  = blockIdx.z;

    __shared__ bf16 KV[2][2][2][64 * 64];  // [buf][h64][K=0 / V^T=1] 64 KB
    __shared__ float Lsc[4][64];           // per-wave row-sum scratch (halves)

    const int tid = threadIdx.x;
    const int lane = tid & 63, wv = tid >> 6;
    const int l31 = lane & 31, hb = lane >> 5;
    const int sw7 = l31 & 7;

    const size_t bnh = (size_t)(n * Hh + h) * Ll * Dd;
    const bf16* __restrict__ Qh = Qt + bnh;
    const bf16* __restrict__ Kh = Kt + bnh;
    const bf16* __restrict__ Vh = Vb + bnh;

    const int srow = tid >> 3;                        // 0..31
    const int scs  = (((tid & 7) ^ (srow & 7)) * 8);  // swizzled global chunk
    const int mhalf = wv & 1;   // which k-half is triangular on this wave's diag

#pragma unroll 1
    for (int ph = 0; ph < 2; ph++) {
        const int st = ph ? (15 - jp) : jp;     // supertile 0..15 (128 q-rows)
        const int nk128 = st + 1;               // 128-wide k-steps
        const int dtile = 2 * st + (wv >> 1);   // diagonal 64-tile index
        const int qrow0 = st * 128 + wv * 32;

        // Q as B-fragments: lane holds Q[q=qrow0+l31][d = s*16 + hb*8 + 0..7]
        bf16x8 qf[4];
#pragma unroll
        for (int s = 0; s < 4; s++)
            qf[s] = *(const bf16x8*)&Qh[(size_t)(qrow0 + l31) * Dd + s * 16 + hb * 8];

        f32x16 O0 = {}, O1 = {};
        float Lacc = 0.f;

        // stage 128-k step 0 -> buf 0 (both 64-subtiles, v13b pattern x2)
#pragma unroll
        for (int h64 = 0; h64 < 2; h64++) {
            const int kn = h64 * 64;
            async16(&Kh[(size_t)(kn + srow) * Dd + scs],      &KV[0][h64][0][(size_t)tid * 8]);
            async16(&Kh[(size_t)(kn + srow + 32) * Dd + scs], &KV[0][h64][0][(size_t)tid * 8 + 2048]);
            async16(&Vh[(size_t)srow * Ll + kn + scs],        &KV[0][h64][1][(size_t)tid * 8]);
            async16(&Vh[(size_t)(srow + 32) * Ll + kn + scs], &KV[0][h64][1][(size_t)tid * 8 + 2048]);
        }
        __syncthreads();   // drains asyncs

        for (int b = 0; b < nk128; b++) {
            const int cur = b & 1;

            if (b + 1 < nk128) {   // prefetch next 128-step into other buffer
#pragma unroll
                for (int h64 = 0; h64 < 2; h64++) {
                    const int kn = (b + 1) * 128 + h64 * 64;
                    async16(&Kh[(size_t)(kn + srow) * Dd + scs],      &KV[cur ^ 1][h64][0][(size_t)tid * 8]);
                    async16(&Kh[(size_t)(kn + srow + 32) * Dd + scs], &KV[cur ^ 1][h64][0][(size_t)tid * 8 + 2048]);
                    async16(&Vh[(size_t)srow * Ll + kn + scs],        &KV[cur ^ 1][h64][1][(size_t)tid * 8]);
                    async16(&Vh[(size_t)(srow + 32) * Ll + kn + scs], &KV[cur ^ 1][h64][1][(size_t)tid * 8 + 2048]);
                }
            }

#pragma unroll
            for (int h64 = 0; h64 < 2; h64++) {
                const int kt = 2 * b + h64;      // 64-granular tile index
                if (kt <= dtile) {               // wave-uniform
                    const bf16* Ks = &KV[cur][h64][0][0];
                    const bf16* Vs = &KV[cur][h64][1][0];
                    const bool dg = (kt == dtile);

#pragma unroll
                    for (int i = 0; i < 2; i++) {
                        // on diag, lower-half waves: upper k-half masked -> skip
                        if (i == 1 && dg && mhalf == 0) continue;

                        // St^T[k = 32i + koff][q = l31], koff = (r&3)+8*(r>>2)+4*hb
                        f32x16 St = {};
#pragma unroll
                        for (int s = 0; s < 4; s++) {
                            bf16x8 kfs = *(const bf16x8*)
                                &Ks[(32 * i + l31) * 64 + (((2 * s + hb) ^ sw7) * 8)];
                            St = MFMA32(kfs, qf[s], St);
                        }

                        const bool msk = dg && (i == mhalf);

#pragma unroll
                        for (int s = 0; s < 2; s++) {
                            // V^T reads (independent of softmax -> issue early)
                            const int c0 = 4 * i + 2 * s + hb;
                            bf16x8 v0 = *(const bf16x8*)&Vs[l31 * 64 + ((c0 ^ sw7) * 8)];
                            bf16x8 v1 = *(const bf16x8*)&Vs[(32 + l31) * 64 + ((c0 ^ sw7) * 8)];

                            float p[8];
#pragma unroll
                            for (int j = 0; j < 8; j++) {
                                const int r = s * 8 + j;
                                float pv = fexp2(St[r]);
                                if (msk) {
                                    const int kc = (r & 3) + 8 * (r >> 2) + 4 * hb;
                                    if (kc > l31) pv = 0.f;
                                }
                                p[j] = pv;
                            }
                            Lacc += ((p[0] + p[1]) + (p[2] + p[3]))
                                  + ((p[4] + p[5]) + (p[6] + p[7]));

                            // lane values after cvtpk (lo-lane / hi-lane):
                            //   A: k(0,1)/k(4,5)  B: k(2,3)/k(6,7)
                            //   C: k(8,9)/k(12,13) D: k(10,11)/k(14,15)
                            u32 A = cvtpk(p[0], p[1]);
                            u32 B = cvtpk(p[2], p[3]);
                            u32 C = cvtpk(p[4], p[5]);
                            u32 D = cvtpk(p[6], p[7]);
                            // dst_hi <-> src_lo:
                            //   A=[A_lo|C_lo], C=[A_hi|C_hi]; B=[B_lo|D_lo], D=[B_hi|D_hi]
                            // lo-lane frag = k(0..7), hi-lane frag = k(8..15)
                            swap32(A, C);
                            swap32(B, D);
                            union { u32 w[4]; bf16x8 v; } pu;
                            pu.w[0] = A; pu.w[1] = B; pu.w[2] = C; pu.w[3] = D;

                            O0 = MFMA32(pu.v, v0, O0);
                            O1 = MFMA32(pu.v, v1, O1);
                        }
                    }
                }
            }

            __syncthreads();   // single barrier: drains prefetch asyncs + flips buffers
        }

        // ---- epilogue: L via LDS half-partials (same-wave DS is in-order;
        // no permlane needed). Lanes l31 and l31+32 hold the two halves of
        // row q = qrow0 + l31. Then normalize in O-row layout and store. ----
        {
            Lsc[wv][hb * 32 + l31] = Lacc;            // write both half-partials
            const float a  = Lsc[wv][l31];            // lo half of row l31
            const float b  = Lsc[wv][32 + l31];       // hi half of row l31
            const float Lt = a + b;
            Lsc[wv][l31] = Lt;                        // both hb write same value

            const size_t aobase = (size_t)n * Ll * Cc + (size_t)h * 64;
#pragma unroll
            for (int r = 0; r < 16; r++) {
                const int qr = (r & 3) + 8 * (r >> 2) + 4 * hb;
                const float inv = 1.0f / Lsc[wv][qr];
                const size_t row = aobase + (size_t)(qrow0 + qr) * Cc;
                AO[row + l31]      = (bf16)(O0[r] * inv);
                AO[row + 32 + l31] = (bf16)(O1[r] * inv);
            }
        }
    }
}

// ---------------------------------------------------------------------------
// Output GEMM (m97 structure, unchanged), fp32 out + bias.
// ---------------------------------------------------------------------------
__global__ __launch_bounds__(256) void out_gemm(
    const bf16* __restrict__ AO, const bf16* __restrict__ Wb,
    const float* __restrict__ bo, float* __restrict__ out)
{
    const int lt = blockIdx.x, ot = blockIdx.y, n = blockIdx.z;

    __shared__ bf16 Ws[128 * 64];
    __shared__ bf16 Bs[128 * 64];

    const int tid = threadIdx.x;
    const int lane = tid & 63, wv = tid >> 6;
    const int m = lane & 15, quad = lane >> 4;
    const int rh = wv & 1, ch = wv >> 1;

    const bf16* __restrict__ W = Wb + 3 * WSZ + (size_t)ot * 128 * Cc;
    const bf16* __restrict__ B = AO + (size_t)(n * Ll + lt * 128) * Cc;

    int srow[4], scol[4];
#pragma unroll
    for (int i = 0; i < 4; i++) {
        int q = i * 256 + tid;
        srow[i] = q >> 3;
        scol[i] = ((q ^ (q >> 3)) & 7) * 8;
    }

    f32x4 acc[4][4] = {};

    for (int c0 = 0; c0 < Cc; c0 += 64) {
#pragma unroll
        for (int i = 0; i < 4; i++)
            async16(&W[(size_t)srow[i] * Cc + c0 + scol[i]], &Ws[(i * 256 + tid) * 8]);
#pragma unroll
        for (int i = 0; i < 4; i++)
            async16(&B[(size_t)srow[i] * Cc + c0 + scol[i]], &Bs[(i * 256 + tid) * 8]);
        __syncthreads();

#pragma unroll
        for (int kk = 0; kk < 2; kk++) {
            const int sw = (((kk * 4 + quad) ^ (m & 7)) * 8);
            bf16x8 af[4], bfr[4];
#pragma unroll
            for (int t = 0; t < 4; t++)
                af[t] = *(const bf16x8*)&Ws[(rh * 64 + t * 16 + m) * 64 + sw];
#pragma unroll
            for (int u = 0; u < 4; u++)
                bfr[u] = *(const bf16x8*)&Bs[(ch * 64 + u * 16 + m) * 64 + sw];
#pragma unroll
            for (int t = 0; t < 4; t++)
#pragma unroll
                for (int u = 0; u < 4; u++)
                    acc[t][u] = MFMA(af[t], bfr[u], acc[t][u]);
        }
        __syncthreads();
    }

#pragma unroll
    for (int t = 0; t < 4; t++) {
        const int ob = ot * 128 + rh * 64 + t * 16 + quad * 4;
#pragma unroll
        for (int r = 0; r < 4; r++) {
            const int o = ob + r;
            const float b = bo[o];
            float* base = out + ((size_t)n * Cc + o) * Ll + lt * 128 + ch * 64;
#pragma unroll
            for (int u = 0; u < 4; u++)
                base[u * 16 + m] = acc[t][u][r] + b;
        }
    }
}

// ---------------------------------------------------------------------------
extern "C" void kernel_launch(void* const* d_in, const int* in_sizes, int n_in,
                              void* d_out, int out_size, void* d_ws, size_t ws_size,
                              hipStream_t stream)
{
    const float* x  = (const float*)d_in[0];
    const float* Wq = (const float*)d_in[1];
    const float* Wk = (const float*)d_in[2];
    const float* Wv = (const float*)d_in[3];
    const float* Wo = (const float*)d_in[4];
    const float* bo = (const float*)d_in[5];
    float* out = (float*)d_out;

    bf16* ws = (bf16*)d_ws;
    bf16* xT = ws;                        // [n][l][c]
    bf16* Wb = xT + NCL;                  // 4 x 512x512
    bf16* Qt = Wb + 4 * WSZ;              // [n][h][l][d]  (pre-scaled)
    bf16* Kt = Qt + NCL;                  // [n][h][l][d]
    bf16* Vb = Kt + NCL;                  // [n][h][d][l]
    bf16* AO = Vb + NCL;                  // [n][l][c]

    prep_kernel<<<dim3(32, 8, Nn + 1), 256, 0, stream>>>(x, Wq, Wk, Wv, Wo, xT, Wb);
    qkv_gemm<<<dim3(16, 12, Nn), 256, 0, stream>>>(xT, Wb, Qt, Kt, Vb);
    attn_mfma<<<dim3(Hh, 8, Nn), 256, 0, stream>>>(Qt, Kt, Vb, AO);
    out_gemm<<<dim3(16, 4, Nn), 256, 0, stream>>>(AO, Wb, bo, out);
}